// Round 8
// baseline (259.442 us; speedup 1.0000x reference)
//
#include <hip/hip_runtime.h>
#include <hip/hip_bf16.h>

#define NN 50000
#define NE 600000
#define DD 128
#define NR 8
#define NCHUNK ((NN + 255) / 256)   // 196 scan blocks

typedef __attribute__((ext_vector_type(8))) short bf16x8;
typedef __attribute__((ext_vector_type(4))) float f32x4;

__device__ __forceinline__ unsigned short f2bf(float f) {
  __hip_bfloat16 h = __float2bfloat16(f);
  return *reinterpret_cast<unsigned short*>(&h);
}
__device__ __forceinline__ unsigned pk2(float lo, float hi) {
  return (unsigned)f2bf(lo) | ((unsigned)f2bf(hi) << 16);
}
__device__ __forceinline__ float bflo(unsigned u) { return __uint_as_float(u << 16); }
__device__ __forceinline__ float bfhi(unsigned u) { return __uint_as_float(u & 0xffff0000u); }

// ---------------- weight transpose+convert: WT[m][o][d] = bf16(W[m][d][o]) ----------------
// m = layer*9 + j ; j<8 relation, j==8 self  (matches gemm's per-layer [9][128][128] view)
__global__ __launch_bounds__(128) void convw_kernel(
    const float* __restrict__ W1, const float* __restrict__ Ws1,
    const float* __restrict__ W2, const float* __restrict__ Ws2,
    unsigned short* __restrict__ WT)
{
  const int m = blockIdx.y, o = blockIdx.x, d = threadIdx.x;
  const float* src;
  if (m < 8)       src = W1 + (size_t)m * DD * DD;
  else if (m == 8) src = Ws1;
  else if (m < 17) src = W2 + (size_t)(m - 9) * DD * DD;
  else             src = Ws2;
  WT[(size_t)m * DD * DD + o * DD + d] = f2bf(src[(size_t)d * DD + o]);
}

// ---------------- h0 = bf16(emb[node_ids]) ----------------
__global__ __launch_bounds__(256) void convh_kernel(
    const float* __restrict__ emb, const int* __restrict__ ids,
    unsigned short* __restrict__ h)
{
  const int gid = blockIdx.x * 256 + threadIdx.x;   // NN*16 total
  if (gid >= NN * 16) return;
  const int row = gid >> 4;
  const int off = (gid & 15) * 8;
  const int srcRow = ids[row];
  const float* src = emb + (size_t)srcRow * DD + off;
  const float4 a = *reinterpret_cast<const float4*>(src);
  const float4 b = *reinterpret_cast<const float4*>(src + 4);
  uint4 u;
  u.x = pk2(a.x, a.y); u.y = pk2(a.z, a.w);
  u.z = pk2(b.x, b.y); u.w = pk2(b.z, b.w);
  *reinterpret_cast<uint4*>(h + (size_t)row * DD + off) = u;
}

// ---------------- CSR build (once per call) ----------------
__global__ __launch_bounds__(256) void hist_kernel(
    const int* __restrict__ dst, int* __restrict__ deg)
{
  const int e = blockIdx.x * 256 + threadIdx.x;
  if (e < NE) atomicAdd(&deg[dst[e]], 1);
}

__global__ __launch_bounds__(256) void bsum_kernel(
    const int* __restrict__ deg, int* __restrict__ bsum)
{
  __shared__ int tmp[256];
  const int t = threadIdx.x;
  const int i = blockIdx.x * 256 + t;
  tmp[t] = (i < NN) ? deg[i] : 0;
  __syncthreads();
#pragma unroll
  for (int off = 128; off > 0; off >>= 1) {
    if (t < off) tmp[t] += tmp[t + off];
    __syncthreads();
  }
  if (t == 0) bsum[blockIdx.x] = tmp[0];
}

__global__ __launch_bounds__(256) void bscan_kernel(
    const int* __restrict__ bsum, int* __restrict__ bbase)
{
  __shared__ int tmp[256];
  const int t = threadIdx.x;
  const int v = (t < NCHUNK) ? bsum[t] : 0;
  tmp[t] = v;
  __syncthreads();
#pragma unroll
  for (int off = 1; off < 256; off <<= 1) {
    const int x = (t >= off) ? tmp[t - off] : 0;
    __syncthreads();
    tmp[t] += x;
    __syncthreads();
  }
  if (t < NCHUNK) bbase[t] = tmp[t] - v;   // exclusive
}

__global__ __launch_bounds__(256) void expand_kernel(
    int* deg, const int* __restrict__ bbase, int* __restrict__ offsets)
{
  __shared__ int tmp[256];
  const int t = threadIdx.x;
  const int i = blockIdx.x * 256 + t;
  const int v = (i < NN) ? deg[i] : 0;
  tmp[t] = v;
  __syncthreads();
#pragma unroll
  for (int off = 1; off < 256; off <<= 1) {
    const int x = (t >= off) ? tmp[t - off] : 0;
    __syncthreads();
    tmp[t] += x;
    __syncthreads();
  }
  const int base = bbase[blockIdx.x];
  const int excl = base + tmp[t] - v;
  if (i < NN) {
    offsets[i] = excl;
    deg[i] = excl;                  // fill cursor
    if (i == NN - 1) offsets[NN] = base + tmp[t];
  }
}

// eidx[pos] = (src << 3) | etype, bucketed by dst
__global__ __launch_bounds__(256) void fill_kernel(
    const int* __restrict__ src, const int* __restrict__ dst,
    const int* __restrict__ et, int* __restrict__ cursor,
    int* __restrict__ eidx)
{
  const int e = blockIdx.x * 256 + threadIdx.x;
  if (e < NE) {
    const int pos = atomicAdd(&cursor[dst[e]], 1);
    eidx[pos] = (src[e] << 3) | et[e];
  }
}

// ---------------- h-space aggregation: s[dst][r][:] = sum of h[src] per relation ----------------
// one wave per dst node; lane owns 2 cols; 8 static relation accumulators (cndmask select)
__global__ __launch_bounds__(256) void agg_kernel(
    const unsigned short* __restrict__ h,
    const int* __restrict__ offsets, const int* __restrict__ eidx,
    unsigned short* __restrict__ s)
{
  const int node = blockIdx.x * 4 + (threadIdx.x >> 6);
  const int lane = threadIdx.x & 63;
  if (node >= NN) return;
  const int beg = offsets[node];
  const int end = offsets[node + 1];

  float ax[NR], ay[NR];
#pragma unroll
  for (int r = 0; r < NR; ++r) { ax[r] = 0.f; ay[r] = 0.f; }

  int e = beg;
  for (; e + 1 < end; e += 2) {
    const int v0 = eidx[e], v1 = eidx[e + 1];
    const unsigned u0 = *reinterpret_cast<const unsigned*>(h + (size_t)(v0 >> 3) * DD + lane * 2);
    const unsigned u1 = *reinterpret_cast<const unsigned*>(h + (size_t)(v1 >> 3) * DD + lane * 2);
    const int e0 = v0 & 7, e1 = v1 & 7;
    const float x0 = bflo(u0), y0 = bfhi(u0), x1 = bflo(u1), y1 = bfhi(u1);
#pragma unroll
    for (int r = 0; r < NR; ++r) {
      ax[r] += ((e0 == r) ? x0 : 0.f) + ((e1 == r) ? x1 : 0.f);
      ay[r] += ((e0 == r) ? y0 : 0.f) + ((e1 == r) ? y1 : 0.f);
    }
  }
  if (e < end) {
    const int v0 = eidx[e];
    const unsigned u0 = *reinterpret_cast<const unsigned*>(h + (size_t)(v0 >> 3) * DD + lane * 2);
    const int e0 = v0 & 7;
    const float x0 = bflo(u0), y0 = bfhi(u0);
#pragma unroll
    for (int r = 0; r < NR; ++r) {
      ax[r] += (e0 == r) ? x0 : 0.f;
      ay[r] += (e0 == r) ? y0 : 0.f;
    }
  }

  unsigned short* srow = s + (size_t)node * (NR * DD) + lane * 2;
#pragma unroll
  for (int r = 0; r < NR; ++r)
    *reinterpret_cast<unsigned*>(srow + r * DD) = pk2(ax[r], ay[r]);
}

// ---------------- fused GEMM: out[n] = sum_r s[n,r]@W_r + h[n]@Wself + b ----------------
// 128 rows/block, 2 n-tiles/wave, W double-buffered in LDS, s-chunks double-buffered in regs.
// No stores inside the K-loop (single epilogue write).
template<int OUTF32>
__global__ __launch_bounds__(256) void gemm_kernel(
    const unsigned short* __restrict__ hbuf,   // [NN][128] self input (bf16)
    const unsigned short* __restrict__ s,      // [NN][8][128] (bf16)
    const unsigned short* __restrict__ WTl,    // this layer: [9][128][128] bf16 [o][d]
    const float* __restrict__ bias,
    void* __restrict__ out)
{
  __shared__ __align__(16) char ldsW[2][DD * DD * 2];   // 2 x 32 KB, XOR-swizzled

  const int tid = threadIdx.x;
  const int rowBase = blockIdx.x * 128;
  const int lane = tid & 63;
  const int w = tid >> 6;
  const int c = lane & 15;
  const int g = lane >> 4;
  int nn[2], nld[2];
#pragma unroll
  for (int u = 0; u < 2; ++u) {
    nn[u] = rowBase + w * 32 + u * 16 + c;
    nld[u] = (nn[u] < NN) ? nn[u] : (NN - 1);
  }

  // staging geometry: dst linear, src pre-inverse-swizzled (byte ^= ((o&7)<<4))
  int srcOff[8];
#pragma unroll
  for (int j = 0; j < 8; ++j) {
    const int dstB = (tid + j * 256) * 16;
    const int srcB = dstB ^ (((dstB >> 8) & 7) << 4);
    srcOff[j] = srcB >> 1;
  }

  // prologue: W[0] -> LDS buf0 ; s-chunk 0 -> sfA
  uint4 wreg[8];
#pragma unroll
  for (int j = 0; j < 8; ++j)
    wreg[j] = *reinterpret_cast<const uint4*>(WTl + srcOff[j]);
#pragma unroll
  for (int j = 0; j < 8; ++j)
    *reinterpret_cast<uint4*>(ldsW[0] + (tid + j * 256) * 16) = wreg[j];

  bf16x8 sfA[2][4], sfB[2][4];
#pragma unroll
  for (int u = 0; u < 2; ++u) {
    const unsigned short* p0 = s + (size_t)nld[u] * (NR * DD);
#pragma unroll
    for (int ks = 0; ks < 4; ++ks)
      sfA[u][ks] = *reinterpret_cast<const bf16x8*>(p0 + ks * 32 + g * 8);
  }

  f32x4 acc[2][8];
#pragma unroll
  for (int u = 0; u < 2; ++u)
#pragma unroll
    for (int t = 0; t < 8; ++t) acc[u][t] = (f32x4){0.f, 0.f, 0.f, 0.f};

#define GSTEP(R, CUR, NXT)                                                            \
  {                                                                                   \
    __syncthreads();                                                                  \
    const char* buf = ldsW[(R) & 1];                                                  \
    if ((R) < NR) {                                                                   \
      const unsigned short* wnext = WTl + (size_t)((R) + 1) * DD * DD;                \
      _Pragma("unroll")                                                               \
      for (int j = 0; j < 8; ++j)                                                     \
        wreg[j] = *reinterpret_cast<const uint4*>(wnext + srcOff[j]);                 \
      _Pragma("unroll")                                                               \
      for (int u = 0; u < 2; ++u) {                                                   \
        const unsigned short* pn = ((R) + 1 < NR)                                     \
            ? s + (size_t)nld[u] * (NR * DD) + ((R) + 1) * DD                         \
            : hbuf + (size_t)nld[u] * DD;                                             \
        _Pragma("unroll")                                                             \
        for (int ks = 0; ks < 4; ++ks)                                                \
          NXT[u][ks] = *reinterpret_cast<const bf16x8*>(pn + ks * 32 + g * 8);        \
      }                                                                               \
    }                                                                                 \
    _Pragma("unroll")                                                                 \
    for (int ks = 0; ks < 4; ++ks) {                                                  \
      _Pragma("unroll")                                                               \
      for (int t = 0; t < 8; ++t) {                                                   \
        const int addr = (((t * 16 + c) << 8) + (ks << 6) + (g << 4)) ^ ((c & 7) << 4); \
        bf16x8 a = *reinterpret_cast<const bf16x8*>(buf + addr);                      \
        acc[0][t] = __builtin_amdgcn_mfma_f32_16x16x32_bf16(a, CUR[0][ks], acc[0][t], 0, 0, 0); \
        acc[1][t] = __builtin_amdgcn_mfma_f32_16x16x32_bf16(a, CUR[1][ks], acc[1][t], 0, 0, 0); \
      }                                                                               \
    }                                                                                 \
    if ((R) < NR) {                                                                   \
      char* nbuf = ldsW[((R) & 1) ^ 1];                                               \
      _Pragma("unroll")                                                               \
      for (int j = 0; j < 8; ++j)                                                     \
        *reinterpret_cast<uint4*>(nbuf + (tid + j * 256) * 16) = wreg[j];             \
    }                                                                                 \
  }

  GSTEP(0, sfA, sfB) GSTEP(1, sfB, sfA) GSTEP(2, sfA, sfB) GSTEP(3, sfB, sfA)
  GSTEP(4, sfA, sfB) GSTEP(5, sfB, sfA) GSTEP(6, sfA, sfB) GSTEP(7, sfB, sfA)
  GSTEP(8, sfA, sfB)
#undef GSTEP

  // epilogue: bias + single store per tile
#pragma unroll
  for (int u = 0; u < 2; ++u) {
    const int n = nn[u];
    if (n >= NN) continue;
    if (OUTF32) {
      float* dst = (float*)out + (size_t)n * DD;
#pragma unroll
      for (int t = 0; t < 8; ++t) {
        const int o0 = t * 16 + g * 4;
        const float4 bv = *reinterpret_cast<const float4*>(bias + o0);
        float4 o;
        o.x = acc[u][t][0] + bv.x; o.y = acc[u][t][1] + bv.y;
        o.z = acc[u][t][2] + bv.z; o.w = acc[u][t][3] + bv.w;
        *reinterpret_cast<float4*>(dst + o0) = o;
      }
    } else {
      unsigned short* dst = (unsigned short*)out + (size_t)n * DD;
#pragma unroll
      for (int t = 0; t < 8; ++t) {
        const int o0 = t * 16 + g * 4;
        const float4 bv = *reinterpret_cast<const float4*>(bias + o0);
        uint2 q;
        q.x = pk2(acc[u][t][0] + bv.x, acc[u][t][1] + bv.y);
        q.y = pk2(acc[u][t][2] + bv.z, acc[u][t][3] + bv.w);
        *reinterpret_cast<uint2*>(dst + o0) = q;
      }
    }
  }
}

extern "C" void kernel_launch(void* const* d_in, const int* in_sizes, int n_in,
                              void* d_out, int out_size, void* d_ws, size_t ws_size,
                              hipStream_t stream) {
  const int*   node_ids = (const int*)d_in[0];
  const int*   src   = (const int*)d_in[1];
  const int*   dst   = (const int*)d_in[2];
  const int*   etype = (const int*)d_in[3];
  const float* emb   = (const float*)d_in[4];
  const float* W1    = (const float*)d_in[5];
  const float* Ws1   = (const float*)d_in[6];
  const float* b1    = (const float*)d_in[7];
  const float* W2    = (const float*)d_in[8];
  const float* Ws2   = (const float*)d_in[9];
  const float* b2    = (const float*)d_in[10];

  // ws layout (~118.5 MB):
  //   s      bf16 [NN*8*DD]      102.4 MB
  //   hbuf   bf16 [NN*DD]         12.8 MB   (h0, overwritten in-place by h1)
  //   WT     bf16 [18*DD*DD]       0.59 MB
  //   offsets i32 [NN+1], deg i32 [NN], eidx i32 [NE], bsum/bbase i32 [256] each
  char* p = (char*)d_ws;
  unsigned short* s    = (unsigned short*)p;  p += (size_t)NN * NR * DD * 2;
  unsigned short* hbuf = (unsigned short*)p;  p += (size_t)NN * DD * 2;
  unsigned short* WT   = (unsigned short*)p;  p += (size_t)18 * DD * DD * 2;
  int* offsets         = (int*)p;             p += (size_t)(NN + 1) * 4;
  int* deg             = (int*)p;             p += (size_t)NN * 4;
  int* eidx            = (int*)p;             p += (size_t)NE * 4;
  int* bsum            = (int*)p;             p += 256 * 4;
  int* bbase           = (int*)p;

  const int eb = (NE + 255) / 256;
  const int tb = (NN + 127) / 128;   // 391
  const int ab = (NN + 3) / 4;       // 12500

  // weight convert + h0 convert + CSR build
  convw_kernel<<<dim3(DD, 18), 128, 0, stream>>>(W1, Ws1, W2, Ws2, WT);
  convh_kernel<<<(NN * 16) / 256, 256, 0, stream>>>(emb, node_ids, hbuf);
  hipMemsetAsync(deg, 0, (size_t)NN * 4, stream);
  hist_kernel<<<eb, 256, 0, stream>>>(dst, deg);
  bsum_kernel<<<NCHUNK, 256, 0, stream>>>(deg, bsum);
  bscan_kernel<<<1, 256, 0, stream>>>(bsum, bbase);
  expand_kernel<<<NCHUNK, 256, 0, stream>>>(deg, bbase, offsets);
  fill_kernel<<<eb, 256, 0, stream>>>(src, dst, etype, deg, eidx);

  // layer 1: s = agg(h0) ; h1 = [s|h0] @ W1stack + b1  (bf16, in-place into hbuf)
  agg_kernel<<<ab, 256, 0, stream>>>(hbuf, offsets, eidx, s);
  gemm_kernel<0><<<tb, 256, 0, stream>>>(hbuf, s, WT, b1, hbuf);
  // layer 2: s = agg(h1) ; out = [s|h1] @ W2stack + b2  (f32)
  agg_kernel<<<ab, 256, 0, stream>>>(hbuf, offsets, eidx, s);
  gemm_kernel<1><<<tb, 256, 0, stream>>>(hbuf, s, WT + (size_t)9 * DD * DD, b2, (float*)d_out);
}